// Round 15
// baseline (141.298 us; speedup 1.0000x reference)
//
#include <hip/hip_runtime.h>
#include <hip/hip_fp16.h>

#define NCELL 4096
#define FRAG_BYTES 14976  // 14336 frag + 640 bias (fp32)

typedef _Float16 f16x8 __attribute__((ext_vector_type(8)));
typedef float f32x4 __attribute__((ext_vector_type(4)));

__device__ __forceinline__ unsigned int packrn(float a, float b) {
    __half2 h = __floats2half2_rn(a, b);
    union { __half2 h; unsigned int u; } x; x.h = h; return x.u;
}

__device__ __forceinline__ int cell_of(float x0, float x1, float x2) {
    int i0 = (int)(x0 / 0.1875f + 8.0f);
    int i1 = (int)(x1 / 0.1875f + 8.0f);
    int i2 = (int)(x2 / 0.1875f + 8.0f);
    i0 = i0 < 0 ? 0 : (i0 > 15 ? 15 : i0);
    i1 = i1 < 0 ? 0 : (i1 > 15 ? 15 : i1);
    i2 = i2 < 0 ? 0 : (i2 > 15 ? 15 : i2);
    return (i0 * 16 + i1) * 16 + i2;
}

__global__ void k_count(const float* __restrict__ xs, int* __restrict__ counts,
                        float* __restrict__ out, int P) {
    int p = blockIdx.x * blockDim.x + threadIdx.x;
    if (p >= P) return;
    float x0 = xs[p * 3 + 0], x1 = xs[p * 3 + 1], x2 = xs[p * 3 + 2];
    bool m = (fabsf(x0) < 1.5f) && (fabsf(x1) < 1.5f) && (fabsf(x2) < 1.5f);
    if (m) {
        atomicAdd(&counts[cell_of(x0, x1, x2)], 1);
    } else {
        out[p * 3 + 0] = 0.0f;
        out[p * 3 + 1] = 0.0f;
        out[p * 3 + 2] = 0.0f;
        out[3 * P + p] = 0.0f;
    }
}

__global__ void k_scan(const int* __restrict__ counts, int* __restrict__ offsets,
                       int* __restrict__ cursor) {
    int l = threadIdx.x;
    const int4* c4 = (const int4*)(counts + l * 64);
    int4 v[16];
#pragma unroll
    for (int k = 0; k < 16; k++) v[k] = c4[k];
    int s = 0;
#pragma unroll
    for (int k = 0; k < 16; k++) s += v[k].x + v[k].y + v[k].z + v[k].w;
    int incl = s;
    for (int d = 1; d < 64; d <<= 1) {
        int t = __shfl_up(incl, d, 64);
        if (l >= d) incl += t;
    }
    int run = incl - s;
#pragma unroll
    for (int k = 0; k < 16; k++) {
        int4 o;
        o.x = run; run += v[k].x;
        o.y = run; run += v[k].y;
        o.z = run; run += v[k].z;
        o.w = run; run += v[k].w;
        ((int4*)(offsets + l * 64))[k] = o;
        ((int4*)(cursor + l * 64))[k] = o;
    }
    if (l == 63) offsets[4096] = run;
}

__global__ void k_scatter(const float* __restrict__ xs, int* __restrict__ cursor,
                          int* __restrict__ sorted, int P) {
    int p = blockIdx.x * blockDim.x + threadIdx.x;
    if (p >= P) return;
    float x0 = xs[p * 3 + 0], x1 = xs[p * 3 + 1], x2 = xs[p * 3 + 2];
    bool m = (fabsf(x0) < 1.5f) && (fabsf(x1) < 1.5f) && (fabsf(x2) < 1.5f);
    if (!m) return;
    int c = cell_of(x0, x1, x2);
    int pos = atomicAdd(&cursor[c], 1);
    sorted[pos] = p;
}

// ---- frag gather from linear fp32 LDS scratch -> GLOBAL frag buffer ----
// dst index == e (identity) -> fully coalesced global writes.
template <int UINTS, int NKS>
__device__ __forceinline__ void gather_fragG(unsigned int* __restrict__ dst,
                                             const float* __restrict__ S,
                                             int Krows, int Ncols, int stride, int tid) {
#pragma unroll
    for (int j = 0; j < UINTS; j++) {
        int e = tid + 256 * j;
        int m = e & 3;
        int l = (e >> 2) & 63;
        int blk = e >> 8;
        int ks = blk % NKS;
        int n = blk / NKS;
        int c = l & 15, gg = l >> 4;
        int k0 = ks * 32 + gg * 8 + 2 * m;
        int col = 16 * n + c;
        int ka = (k0 < Krows) ? k0 : (Krows - 1);
        int kb = (k0 + 1 < Krows) ? (k0 + 1) : (Krows - 1);
        int cc = (col < Ncols) ? col : (Ncols - 1);
        dst[e] = packrn(S[ka * stride + cc], S[kb * stride + cc]);
    }
}

// One block per cell: fp32 weights -> f16 frag-linear + fp32 bias in d_ws.
__global__ void __launch_bounds__(256) k_prep(
    const float* __restrict__ w1g, const float* __restrict__ b1g,
    const float* __restrict__ w2g, const float* __restrict__ b2g,
    const float* __restrict__ w3g, const float* __restrict__ b3g,
    const float* __restrict__ w4g, const float* __restrict__ b4g,
    const float* __restrict__ w5g, const float* __restrict__ b5g,
    char* __restrict__ wfrag) {
    __shared__ __align__(16) float4 scr[1024];
    int cell = blockIdx.x;
    int tid = threadIdx.x;
    char* dst = wfrag + (size_t)cell * FRAG_BYTES;

    // Round A: W1 (504 f4) | W2 (264 f4)
    {
        const float4* W1v = (const float4*)(w1g + (size_t)cell * 2016);
        const float4* W2v = (const float4*)(w2g + (size_t)cell * 1056);
        int e1 = tid + 256, e2 = tid + 512;
        float4 r0 = (tid < 504) ? W1v[tid] : W2v[tid - 504];
        float4 r1 = (e1 < 504) ? W1v[e1] : W2v[e1 - 504];
        float4 r2 = (e2 < 504) ? W1v[e2] : W2v[e2 - 504];
        scr[tid] = r0; scr[e1] = r1; scr[e2] = r2;
    }
    __syncthreads();
    gather_fragG<4, 2>((unsigned int*)(dst + 0),    (const float*)scr, 63, 32, 32, tid);
    gather_fragG<3, 1>((unsigned int*)(dst + 4096), (const float*)scr + 2016, 32, 33, 33, tid);
    __syncthreads();

    // Round B: W3 (256 f4) | W4 (472 f4)
    {
        const float4* W3v = (const float4*)(w3g + (size_t)cell * 1024);
        const float4* W4v = (const float4*)(w4g + (size_t)cell * 1888);
        int e2 = tid + 512;
        if (tid < 256) scr[tid] = W3v[tid];
        scr[tid + 256] = W4v[tid];
        if (e2 < 728) scr[e2] = W4v[tid + 256];
    }
    __syncthreads();
    gather_fragG<2, 1>((unsigned int*)(dst + 7168), (const float*)scr, 32, 32, 32, tid);
    gather_fragG<4, 2>((unsigned int*)(dst + 9216), (const float*)scr + 1024, 59, 32, 32, tid);
    __syncthreads();

    // Round C: W5 + bias (bias written straight to global, fp32)
    {
        const float4* W5v = (const float4*)(w5g + (size_t)cell * 96);
        if (tid < 24) scr[tid] = W5v[tid];
        if (tid >= 64 && tid < 224) {
            int e = tid - 64;
            float v = 0.0f;
            if (e < 32) v = b1g[(size_t)cell * 32 + e];
            else if (e < 80) { int q = e - 32; v = (q < 33) ? b2g[(size_t)cell * 33 + q] : 0.0f; }
            else if (e < 112) v = b3g[(size_t)cell * 32 + (e - 80)];
            else if (e < 144) v = b4g[(size_t)cell * 32 + (e - 112)];
            else { int q = e - 144; v = (q < 3) ? b5g[(size_t)cell * 3 + q] : 0.0f; }
            ((float*)(dst + 14336))[e] = v;
        }
    }
    __syncthreads();
    gather_fragG<1, 1>((unsigned int*)(dst + 13312), (const float*)scr, 32, 3, 3, tid);
}

// ---- MFMA act helpers (validated R10-R13) ----
__device__ __forceinline__ f16x8 ldA(const char* act, int lane, int ks) {
    int p = lane & 15, g = lane >> 4;
    int byte = (p * 128 + ks * 64 + g * 16) ^ ((p & 7) << 4);
    return *(const f16x8*)(act + byte);
}
__device__ __forceinline__ void stD(char* act, int kcol, f32x4 acc, bool relu, int g4) {
#pragma unroll
    for (int r = 0; r < 4; r++) {
        int p = g4 * 4 + r;
        float v = acc[r];
        if (relu) v = fmaxf(v, 0.0f);
        *(_Float16*)(act + ((p * 128 + kcol * 2) ^ ((p & 7) << 4))) = (_Float16)v;
    }
}

#define MFMA16(a, b, c) __builtin_amdgcn_mfma_f32_16x16x32_f16((a), (b), (c), 0, 0, 0)

// One wave per cell, zero barriers. Weights live in registers (14 B-frags
// loaded once per cell via coalesced dwordx4); only act transposes touch LDS.
__global__ void __launch_bounds__(256, 4) k_mlp_frag(
    const float* __restrict__ xs, const float* __restrict__ dvs,
    const char* __restrict__ wfrag,
    const int* __restrict__ offsets, const int* __restrict__ sorted,
    float* __restrict__ out, int P) {
    __shared__ __align__(16) char act[4][4096];
    __shared__ float sig[64];
    __shared__ int idxL[64];

    int tid = threadIdx.x;
    int lane = tid & 63;
    int wid = tid >> 6;
    int cell = blockIdx.x * 4 + wid;
    int start = offsets[cell], end = offsets[cell + 1];
    if (start >= end) return;
    int cidx = lane & 15;
    int g4 = lane >> 4;

    const char* wc = wfrag + (size_t)cell * FRAG_BYTES;
    f16x8 F[14];
#pragma unroll
    for (int b = 0; b < 14; b++) F[b] = *(const f16x8*)(wc + b * 1024 + lane * 16);
    const float* bs = (const float*)(wc + 14336);
    float bL1[2] = {bs[cidx], bs[16 + cidx]};
    float bL2[3] = {bs[32 + cidx], bs[48 + cidx], bs[64 + cidx]};
    float bL3[2] = {bs[80 + cidx], bs[96 + cidx]};
    float bL4[2] = {bs[112 + cidx], bs[128 + cidx]};
    float bL5 = bs[144 + cidx];

    char* actA = act[wid];
    char* actB = act[wid] + 2048;
    float* sigw = sig + (wid << 4);
    int* idxw = idxL + (wid << 4);

    for (int t0 = start; t0 < end; t0 += 16) {
        int nv = end - t0; if (nv > 16) nv = 16;
        int t = t0 + cidx;
        int idx = sorted[(cidx < nv) ? t : start];
        if (g4 == 0) idxw[cidx] = idx;
        float x0 = xs[idx * 3 + 0], x1 = xs[idx * 3 + 1], x2 = xs[idx * 3 + 2];
        float d0 = dvs[idx * 3 + 0], d1 = dvs[idx * 3 + 1], d2 = dvs[idx * 3 + 2];

        // positional encoding -> actA[p][0..63]
        {
            float ev[16];
#pragma unroll
            for (int i = 0; i < 16; i++) {
                int k = g4 * 16 + i;
                float v;
                if (k < 3) v = (k == 0) ? x0 : ((k == 1) ? x1 : x2);
                else if (k < 63) {
                    int q = k - 3, j = q / 6, r = q % 6, a = r % 3;
                    float xx = (a == 0) ? x0 : ((a == 1) ? x1 : x2);
                    float arg = (float)(1 << j) * xx;
                    v = (r < 3) ? __sinf(arg) : __cosf(arg);
                } else v = 0.0f;
                ev[i] = v;
            }
            uint4 u0, u1;
            u0.x = packrn(ev[0], ev[1]);  u0.y = packrn(ev[2], ev[3]);
            u0.z = packrn(ev[4], ev[5]);  u0.w = packrn(ev[6], ev[7]);
            u1.x = packrn(ev[8], ev[9]);  u1.y = packrn(ev[10], ev[11]);
            u1.z = packrn(ev[12], ev[13]); u1.w = packrn(ev[14], ev[15]);
            int sw = (cidx & 7) << 4;
            *(uint4*)(actA + ((cidx * 128 + g4 * 32) ^ sw)) = u0;
            *(uint4*)(actA + ((cidx * 128 + g4 * 32 + 16) ^ sw)) = u1;
        }
        // direction encoding -> actB[p][32..63]
        {
            float ev[8];
#pragma unroll
            for (int i = 0; i < 8; i++) {
                int k = g4 * 8 + i;
                float v;
                if (k < 3) v = (k == 0) ? d0 : ((k == 1) ? d1 : d2);
                else if (k < 27) {
                    int q = k - 3, j = q / 6, r = q % 6, a = r % 3;
                    float xx = (a == 0) ? d0 : ((a == 1) ? d1 : d2);
                    float arg = (float)(1 << j) * xx;
                    v = (r < 3) ? __sinf(arg) : __cosf(arg);
                } else v = 0.0f;
                ev[i] = v;
            }
            uint4 u;
            u.x = packrn(ev[0], ev[1]); u.y = packrn(ev[2], ev[3]);
            u.z = packrn(ev[4], ev[5]); u.w = packrn(ev[6], ev[7]);
            *(uint4*)(actB + ((cidx * 128 + 64 + g4 * 16) ^ ((cidx & 7) << 4))) = u;
        }

        // L1: enc(64) -> 32, relu -> actB[0..31]
        {
            f16x8 a0 = ldA(actA, lane, 0);
            f16x8 a1 = ldA(actA, lane, 1);
#pragma unroll
            for (int n = 0; n < 2; n++) {
                float bv = bL1[n];
                f32x4 acc = {bv, bv, bv, bv};
                acc = MFMA16(a0, F[n * 2 + 0], acc);
                acc = MFMA16(a1, F[n * 2 + 1], acc);
                stD(actB, 16 * n + cidx, acc, true, g4);
            }
        }
        // L2: 32 -> 33, relu; col0 -> sigma; cols1..32 -> actA
        {
            f16x8 a2 = ldA(actB, lane, 0);
#pragma unroll
            for (int n = 0; n < 3; n++) {
                float bv = bL2[n];
                f32x4 acc = {bv, bv, bv, bv};
                acc = MFMA16(a2, F[4 + n], acc);
                int C = 16 * n + cidx;
                if (C == 0) {
#pragma unroll
                    for (int r = 0; r < 4; r++) sigw[g4 * 4 + r] = fmaxf(acc[r], 0.0f);
                } else if (C <= 32) {
                    stD(actA, C - 1, acc, true, g4);
                }
            }
        }
        // L3: 32 -> 32 -> actB
        {
            f16x8 a3 = ldA(actA, lane, 0);
#pragma unroll
            for (int n = 0; n < 2; n++) {
                float bv = bL3[n];
                f32x4 acc = {bv, bv, bv, bv};
                acc = MFMA16(a3, F[7 + n], acc);
                stD(actB, 16 * n + cidx, acc, false, g4);
            }
        }
        // L4: 64 -> 32, relu -> actA
        {
            f16x8 a4a = ldA(actB, lane, 0);
            f16x8 a4b = ldA(actB, lane, 1);
#pragma unroll
            for (int n = 0; n < 2; n++) {
                float bv = bL4[n];
                f32x4 acc = {bv, bv, bv, bv};
                acc = MFMA16(a4a, F[9 + n * 2], acc);
                acc = MFMA16(a4b, F[9 + n * 2 + 1], acc);
                stD(actA, 16 * n + cidx, acc, true, g4);
            }
        }
        // L5: 32 -> 3, sigmoid; + sigma
        {
            f16x8 a5 = ldA(actA, lane, 0);
            f32x4 acc = {bL5, bL5, bL5, bL5};
            acc = MFMA16(a5, F[13], acc);
            if (cidx < 3) {
#pragma unroll
                for (int r = 0; r < 4; r++) {
                    int p = g4 * 4 + r;
                    if (p < nv) out[(size_t)idxw[p] * 3 + cidx] = 1.0f / (1.0f + __expf(-acc[r]));
                }
            } else if (cidx == 3) {
#pragma unroll
                for (int r = 0; r < 4; r++) {
                    int p = g4 * 4 + r;
                    if (p < nv) out[(size_t)3 * P + idxw[p]] = sigw[p];
                }
            }
        }
    }
}

// ---- fallback (R12, 61 us validated) ----
__device__ __forceinline__ f16x8 ldB(const char* wb, int off, int blk, int lane) {
    return *(const f16x8*)(wb + off + blk * 1024 + lane * 16);
}
template <int ITERS, int NKS>
__device__ __forceinline__ void stage_fragC(char* wb, int off,
                                            const float* __restrict__ W,
                                            int Krows, int Ncols, int stride,
                                            int tid) {
    float va[ITERS], vb[ITERS];
    unsigned int* dst = (unsigned int*)(wb + off);
#pragma unroll
    for (int j = 0; j < ITERS; j++) {
        int e = tid + 256 * j;
        int m = e & 3;
        int l = (e >> 2) & 63;
        int blk = e >> 8;
        int ks = blk % NKS;
        int n = blk / NKS;
        int c = l & 15, gg = l >> 4;
        int k0 = ks * 32 + gg * 8 + 2 * m;
        int col = 16 * n + c;
        int ka = (k0 < Krows) ? k0 : (Krows - 1);
        int kb = (k0 + 1 < Krows) ? (k0 + 1) : (Krows - 1);
        int cc = (col < Ncols) ? col : (Ncols - 1);
        va[j] = W[ka * stride + cc];
        vb[j] = W[kb * stride + cc];
    }
#pragma unroll
    for (int j = 0; j < ITERS; j++) {
        int e = tid + 256 * j;
        int m = e & 3;
        int l = (e >> 2) & 63;
        int blk = e >> 8;
        dst[blk * 256 + l * 4 + m] = packrn(va[j], vb[j]);
    }
}

__global__ void __launch_bounds__(256) k_mlp_lds(
    const float* __restrict__ xs, const float* __restrict__ dvs,
    const float* __restrict__ w1g, const float* __restrict__ b1g,
    const float* __restrict__ w2g, const float* __restrict__ b2g,
    const float* __restrict__ w3g, const float* __restrict__ b3g,
    const float* __restrict__ w4g, const float* __restrict__ b4g,
    const float* __restrict__ w5g, const float* __restrict__ b5g,
    const int* __restrict__ offsets, const int* __restrict__ sorted,
    float* __restrict__ out, int P) {
    __shared__ __align__(16) char wB[14336];
    __shared__ __align__(16) char actAall[8192];
    __shared__ __align__(16) char actBall[8192];
    __shared__ float bias[160];
    __shared__ float sig[64];
    __shared__ int idxL[64];

    int cell = blockIdx.x;
    int start = offsets[cell], end = offsets[cell + 1];
    if (start >= end) return;
    int tid = threadIdx.x;
    int lane = tid & 63;
    int wid = tid >> 6;
    int cidx = lane & 15;
    int g4 = lane >> 4;

    stage_fragC<4, 2>(wB, 0,     w1g + (size_t)cell * 2016, 63, 32, 32, tid);
    stage_fragC<3, 1>(wB, 4096,  w2g + (size_t)cell * 1056, 32, 33, 33, tid);
    stage_fragC<2, 1>(wB, 7168,  w3g + (size_t)cell * 1024, 32, 32, 32, tid);
    stage_fragC<4, 2>(wB, 9216,  w4g + (size_t)cell * 1888, 59, 32, 32, tid);
    stage_fragC<1, 1>(wB, 13312, w5g + (size_t)cell * 96,   32, 3, 3, tid);
    if (tid < 160) {
        int e = tid;
        float v = 0.0f;
        if (e < 32) v = b1g[(size_t)cell * 32 + e];
        else if (e < 80) { int q = e - 32; v = (q < 33) ? b2g[(size_t)cell * 33 + q] : 0.0f; }
        else if (e < 112) v = b3g[(size_t)cell * 32 + (e - 80)];
        else if (e < 144) v = b4g[(size_t)cell * 32 + (e - 112)];
        else { int q = e - 144; v = (q < 3) ? b5g[(size_t)cell * 3 + q] : 0.0f; }
        bias[e] = v;
    }
    __syncthreads();

    char* actA = actAall + (wid << 11);
    char* actB = actBall + (wid << 11);
    float* sigw = sig + (wid << 4);
    int* idxw = idxL + (wid << 4);

    for (int t0 = start + (wid << 4); t0 < end; t0 += 64) {
        int nv = end - t0; if (nv > 16) nv = 16;
        int t = t0 + cidx;
        int idx = sorted[(cidx < nv) ? t : start];
        if (g4 == 0) idxw[cidx] = idx;
        float x0 = xs[idx * 3 + 0], x1 = xs[idx * 3 + 1], x2 = xs[idx * 3 + 2];
        float d0 = dvs[idx * 3 + 0], d1 = dvs[idx * 3 + 1], d2 = dvs[idx * 3 + 2];
        {
            float ev[16];
#pragma unroll
            for (int i = 0; i < 16; i++) {
                int k = g4 * 16 + i;
                float v;
                if (k < 3) v = (k == 0) ? x0 : ((k == 1) ? x1 : x2);
                else if (k < 63) {
                    int q = k - 3, j = q / 6, r = q % 6, a = r % 3;
                    float xx = (a == 0) ? x0 : ((a == 1) ? x1 : x2);
                    float arg = (float)(1 << j) * xx;
                    v = (r < 3) ? __sinf(arg) : __cosf(arg);
                } else v = 0.0f;
                ev[i] = v;
            }
            uint4 u0, u1;
            u0.x = packrn(ev[0], ev[1]);  u0.y = packrn(ev[2], ev[3]);
            u0.z = packrn(ev[4], ev[5]);  u0.w = packrn(ev[6], ev[7]);
            u1.x = packrn(ev[8], ev[9]);  u1.y = packrn(ev[10], ev[11]);
            u1.z = packrn(ev[12], ev[13]); u1.w = packrn(ev[14], ev[15]);
            int sw = (cidx & 7) << 4;
            *(uint4*)(actA + ((cidx * 128 + g4 * 32) ^ sw)) = u0;
            *(uint4*)(actA + ((cidx * 128 + g4 * 32 + 16) ^ sw)) = u1;
        }
        {
            float ev[8];
#pragma unroll
            for (int i = 0; i < 8; i++) {
                int k = g4 * 8 + i;
                float v;
                if (k < 3) v = (k == 0) ? d0 : ((k == 1) ? d1 : d2);
                else if (k < 27) {
                    int q = k - 3, j = q / 6, r = q % 6, a = r % 3;
                    float xx = (a == 0) ? d0 : ((a == 1) ? d1 : d2);
                    float arg = (float)(1 << j) * xx;
                    v = (r < 3) ? __sinf(arg) : __cosf(arg);
                } else v = 0.0f;
                ev[i] = v;
            }
            uint4 u;
            u.x = packrn(ev[0], ev[1]); u.y = packrn(ev[2], ev[3]);
            u.z = packrn(ev[4], ev[5]); u.w = packrn(ev[6], ev[7]);
            *(uint4*)(actB + ((cidx * 128 + 64 + g4 * 16) ^ ((cidx & 7) << 4))) = u;
        }
        {
            f16x8 a0 = ldA(actA, lane, 0);
            f16x8 a1 = ldA(actA, lane, 1);
#pragma unroll
            for (int n = 0; n < 2; n++) {
                float bv = bias[0 + 16 * n + cidx];
                f32x4 acc = {bv, bv, bv, bv};
                acc = MFMA16(a0, ldB(wB, 0, n * 2 + 0, lane), acc);
                acc = MFMA16(a1, ldB(wB, 0, n * 2 + 1, lane), acc);
                stD(actB, 16 * n + cidx, acc, true, g4);
            }
        }
        {
            f16x8 a2 = ldA(actB, lane, 0);
#pragma unroll
            for (int n = 0; n < 3; n++) {
                float bv = bias[32 + 16 * n + cidx];
                f32x4 acc = {bv, bv, bv, bv};
                acc = MFMA16(a2, ldB(wB, 4096, n, lane), acc);
                int C = 16 * n + cidx;
                if (C == 0) {
#pragma unroll
                    for (int r = 0; r < 4; r++) sigw[g4 * 4 + r] = fmaxf(acc[r], 0.0f);
                } else if (C <= 32) {
                    stD(actA, C - 1, acc, true, g4);
                }
            }
        }
        {
            f16x8 a3 = ldA(actA, lane, 0);
#pragma unroll
            for (int n = 0; n < 2; n++) {
                float bv = bias[80 + 16 * n + cidx];
                f32x4 acc = {bv, bv, bv, bv};
                acc = MFMA16(a3, ldB(wB, 7168, n, lane), acc);
                stD(actB, 16 * n + cidx, acc, false, g4);
            }
        }
        {
            f16x8 a4a = ldA(actB, lane, 0);
            f16x8 a4b = ldA(actB, lane, 1);
#pragma unroll
            for (int n = 0; n < 2; n++) {
                float bv = bias[112 + 16 * n + cidx];
                f32x4 acc = {bv, bv, bv, bv};
                acc = MFMA16(a4a, ldB(wB, 9216, n * 2 + 0, lane), acc);
                acc = MFMA16(a4b, ldB(wB, 9216, n * 2 + 1, lane), acc);
                stD(actA, 16 * n + cidx, acc, true, g4);
            }
        }
        {
            f16x8 a5 = ldA(actA, lane, 0);
            float bv = bias[144 + cidx];
            f32x4 acc = {bv, bv, bv, bv};
            acc = MFMA16(a5, ldB(wB, 13312, 0, lane), acc);
            if (cidx < 3) {
#pragma unroll
                for (int r = 0; r < 4; r++) {
                    int p = g4 * 4 + r;
                    if (p < nv) out[(size_t)idxw[p] * 3 + cidx] = 1.0f / (1.0f + __expf(-acc[r]));
                }
            } else if (cidx == 3) {
#pragma unroll
                for (int r = 0; r < 4; r++) {
                    int p = g4 * 4 + r;
                    if (p < nv) out[(size_t)3 * P + idxw[p]] = sigw[p];
                }
            }
        }
    }
}

extern "C" void kernel_launch(void* const* d_in, const int* in_sizes, int n_in,
                              void* d_out, int out_size, void* d_ws, size_t ws_size,
                              hipStream_t stream) {
    const float* xs = (const float*)d_in[0];
    const float* dv = (const float*)d_in[1];
    const float* w1 = (const float*)d_in[2];
    const float* b1 = (const float*)d_in[3];
    const float* w2 = (const float*)d_in[4];
    const float* b2 = (const float*)d_in[5];
    const float* w3 = (const float*)d_in[6];
    const float* b3 = (const float*)d_in[7];
    const float* w4 = (const float*)d_in[8];
    const float* b4 = (const float*)d_in[9];
    const float* w5 = (const float*)d_in[10];
    const float* b5 = (const float*)d_in[11];
    float* out = (float*)d_out;
    int P = in_sizes[0] / 3;

    int* counts = (int*)d_ws;
    int* offsets = counts + 4096;
    int* cursor = offsets + 4104;
    int* sorted = cursor + 4096;

    size_t idx_bytes = (size_t)(4096 + 4104 + 4096 + P) * 4;
    size_t wfrag_off = (idx_bytes + 63) & ~(size_t)63;
    size_t need = wfrag_off + (size_t)NCELL * FRAG_BYTES;
    bool big = ws_size >= need;
    char* wfrag = (char*)d_ws + wfrag_off;

    hipMemsetAsync(counts, 0, 4096 * sizeof(int), stream);

    if (big) {
        k_prep<<<NCELL, 256, 0, stream>>>(w1, b1, w2, b2, w3, b3, w4, b4, w5, b5, wfrag);
    }
    int blk = 256;
    int grd = (P + blk - 1) / blk;
    k_count<<<grd, blk, 0, stream>>>(xs, counts, out, P);
    k_scan<<<1, 64, 0, stream>>>(counts, offsets, cursor);
    k_scatter<<<grd, blk, 0, stream>>>(xs, cursor, sorted, P);
    if (big) {
        k_mlp_frag<<<NCELL / 4, 256, 0, stream>>>(xs, dv, wfrag, offsets, sorted, out, P);
    } else {
        k_mlp_lds<<<NCELL, 256, 0, stream>>>(xs, dv, w1, b1, w2, b2, w3, b3, w4, b4, w5, b5,
                                             offsets, sorted, out, P);
    }
}

// Round 16
// 70.611 us; speedup vs baseline: 2.0011x; 2.0011x over previous
//
#include <hip/hip_runtime.h>
#include <hip/hip_fp16.h>

#define NCELL 4096

typedef _Float16 f16x8 __attribute__((ext_vector_type(8)));
typedef float f32x4 __attribute__((ext_vector_type(4)));

__device__ __forceinline__ unsigned int packrn(float a, float b) {
    __half2 h = __floats2half2_rn(a, b);
    union { __half2 h; unsigned int u; } x; x.h = h; return x.u;
}

__device__ __forceinline__ int cell_of(float x0, float x1, float x2) {
    int i0 = (int)(x0 / 0.1875f + 8.0f);
    int i1 = (int)(x1 / 0.1875f + 8.0f);
    int i2 = (int)(x2 / 0.1875f + 8.0f);
    i0 = i0 < 0 ? 0 : (i0 > 15 ? 15 : i0);
    i1 = i1 < 0 ? 0 : (i1 > 15 ? 15 : i1);
    i2 = i2 < 0 ? 0 : (i2 > 15 ? 15 : i2);
    return (i0 * 16 + i1) * 16 + i2;
}

// counts actives per cell, zero-fills masked outputs, caches cellid.
__global__ void k_count(const float* __restrict__ xs, int* __restrict__ counts,
                        int* __restrict__ cellid, float* __restrict__ out, int P) {
    int p = blockIdx.x * blockDim.x + threadIdx.x;
    if (p >= P) return;
    float x0 = xs[p * 3 + 0], x1 = xs[p * 3 + 1], x2 = xs[p * 3 + 2];
    bool m = (fabsf(x0) < 1.5f) && (fabsf(x1) < 1.5f) && (fabsf(x2) < 1.5f);
    if (m) {
        int c = cell_of(x0, x1, x2);
        cellid[p] = c;
        atomicAdd(&counts[c], 1);
    } else {
        cellid[p] = -1;
        out[p * 3 + 0] = 0.0f;
        out[p * 3 + 1] = 0.0f;
        out[p * 3 + 2] = 0.0f;
        out[3 * P + p] = 0.0f;
    }
}

__global__ void k_scan(const int* __restrict__ counts, int* __restrict__ offsets,
                       int* __restrict__ cursor) {
    int l = threadIdx.x;
    const int4* c4 = (const int4*)(counts + l * 64);
    int4 v[16];
#pragma unroll
    for (int k = 0; k < 16; k++) v[k] = c4[k];
    int s = 0;
#pragma unroll
    for (int k = 0; k < 16; k++) s += v[k].x + v[k].y + v[k].z + v[k].w;
    int incl = s;
    for (int d = 1; d < 64; d <<= 1) {
        int t = __shfl_up(incl, d, 64);
        if (l >= d) incl += t;
    }
    int run = incl - s;
#pragma unroll
    for (int k = 0; k < 16; k++) {
        int4 o;
        o.x = run; run += v[k].x;
        o.y = run; run += v[k].y;
        o.z = run; run += v[k].z;
        o.w = run; run += v[k].w;
        ((int4*)(offsets + l * 64))[k] = o;
        ((int4*)(cursor + l * 64))[k] = o;
    }
    if (l == 63) offsets[4096] = run;
}

__global__ void k_scatter(const int* __restrict__ cellid, int* __restrict__ cursor,
                          int* __restrict__ sorted, int P) {
    int p = blockIdx.x * blockDim.x + threadIdx.x;
    if (p >= P) return;
    int c = cellid[p];
    if (c < 0) return;
    int pos = atomicAdd(&cursor[c], 1);
    sorted[pos] = p;
}

// ---- MFMA helpers (validated R10-R13) ----
__device__ __forceinline__ f16x8 ldB(const char* wb, int off, int blk, int lane) {
    return *(const f16x8*)(wb + off + blk * 1024 + lane * 16);
}
__device__ __forceinline__ f16x8 ldA(const char* act, int lane, int ks) {
    int p = lane & 15, g = lane >> 4;
    int byte = (p * 128 + ks * 64 + g * 16) ^ ((p & 7) << 4);
    return *(const f16x8*)(act + byte);
}
__device__ __forceinline__ void stD(char* act, int kcol, f32x4 acc, bool relu, int g4) {
#pragma unroll
    for (int r = 0; r < 4; r++) {
        int p = g4 * 4 + r;
        float v = acc[r];
        if (relu) v = fmaxf(v, 0.0f);
        *(_Float16*)(act + ((p * 128 + kcol * 2) ^ ((p & 7) << 4))) = (_Float16)v;
    }
}

// Batched staging (validated R12): phase 1 issues all independent global
// loads into compile-time-indexed registers; phase 2 packs + ds_writes.
template <int ITERS, int NKS>
__device__ __forceinline__ void stage_fragC(char* wb, int off,
                                            const float* __restrict__ W,
                                            int Krows, int Ncols, int stride,
                                            int tid) {
    float va[ITERS], vb[ITERS];
    unsigned int* dst = (unsigned int*)(wb + off);
#pragma unroll
    for (int j = 0; j < ITERS; j++) {
        int e = tid + 256 * j;
        int m = e & 3;
        int l = (e >> 2) & 63;
        int blk = e >> 8;
        int ks = blk % NKS;
        int n = blk / NKS;
        int c = l & 15, gg = l >> 4;
        int k0 = ks * 32 + gg * 8 + 2 * m;
        int col = 16 * n + c;
        int ka = (k0 < Krows) ? k0 : (Krows - 1);
        int kb = (k0 + 1 < Krows) ? (k0 + 1) : (Krows - 1);
        int cc = (col < Ncols) ? col : (Ncols - 1);
        va[j] = W[ka * stride + cc];
        vb[j] = W[kb * stride + cc];
    }
#pragma unroll
    for (int j = 0; j < ITERS; j++) {
        int e = tid + 256 * j;
        int m = e & 3;
        int l = (e >> 2) & 63;
        int blk = e >> 8;
        dst[blk * 256 + l * 4 + m] = packrn(va[j], vb[j]);
    }
}

#define MFMA16(a, b, c) __builtin_amdgcn_mfma_f32_16x16x32_f16((a), (b), (c), 0, 0, 0)

// 4 waves/block, one cell/block (R12 structure) with SINGLE 2KB act buffer
// per wave: each layer fully ldA's its input into registers before stD'ing
// its output; dir-enc parks at pre-swizzle bytes [64,128)/row from L1 to L4.
// LDS/block ~23.7 KB -> 6 blocks/CU.
__global__ void __launch_bounds__(256) k_mlp(
    const float* __restrict__ xs, const float* __restrict__ dvs,
    const float* __restrict__ w1g, const float* __restrict__ b1g,
    const float* __restrict__ w2g, const float* __restrict__ b2g,
    const float* __restrict__ w3g, const float* __restrict__ b3g,
    const float* __restrict__ w4g, const float* __restrict__ b4g,
    const float* __restrict__ w5g, const float* __restrict__ b5g,
    const int* __restrict__ offsets, const int* __restrict__ sorted,
    float* __restrict__ out, int P) {
    __shared__ __align__(16) char wB[14336];
    __shared__ __align__(16) char actAll[4][2048];
    __shared__ float bias[160];
    __shared__ float sig[64];
    __shared__ int idxL[64];

    int cell = blockIdx.x;
    int start = offsets[cell], end = offsets[cell + 1];
    if (start >= end) return;
    int tid = threadIdx.x;
    int lane = tid & 63;
    int wid = tid >> 6;
    int cidx = lane & 15;
    int g4 = lane >> 4;

    stage_fragC<4, 2>(wB, 0,     w1g + (size_t)cell * 2016, 63, 32, 32, tid);
    stage_fragC<3, 1>(wB, 4096,  w2g + (size_t)cell * 1056, 32, 33, 33, tid);
    stage_fragC<2, 1>(wB, 7168,  w3g + (size_t)cell * 1024, 32, 32, 32, tid);
    stage_fragC<4, 2>(wB, 9216,  w4g + (size_t)cell * 1888, 59, 32, 32, tid);
    stage_fragC<1, 1>(wB, 13312, w5g + (size_t)cell * 96,   32, 3, 3, tid);
    if (tid < 160) {
        int e = tid;
        float v = 0.0f;
        if (e < 32) v = b1g[(size_t)cell * 32 + e];
        else if (e < 80) { int q = e - 32; v = (q < 33) ? b2g[(size_t)cell * 33 + q] : 0.0f; }
        else if (e < 112) v = b3g[(size_t)cell * 32 + (e - 80)];
        else if (e < 144) v = b4g[(size_t)cell * 32 + (e - 112)];
        else { int q = e - 144; v = (q < 3) ? b5g[(size_t)cell * 3 + q] : 0.0f; }
        bias[e] = v;
    }
    __syncthreads();

    char* buf = actAll[wid];
    float* sigw = sig + (wid << 4);
    int* idxw = idxL + (wid << 4);

    for (int t0 = start + (wid << 4); t0 < end; t0 += 64) {
        int nv = end - t0; if (nv > 16) nv = 16;
        int t = t0 + cidx;
        int idx = sorted[(cidx < nv) ? t : start];
        if (g4 == 0) idxw[cidx] = idx;
        float x0 = xs[idx * 3 + 0], x1 = xs[idx * 3 + 1], x2 = xs[idx * 3 + 2];
        float d0 = dvs[idx * 3 + 0], d1 = dvs[idx * 3 + 1], d2 = dvs[idx * 3 + 2];

        // ---- positional encoding -> buf[p][0..63] (all 64 k-cols)
        {
            float ev[16];
#pragma unroll
            for (int i = 0; i < 16; i++) {
                int k = g4 * 16 + i;
                float v;
                if (k < 3) v = (k == 0) ? x0 : ((k == 1) ? x1 : x2);
                else if (k < 63) {
                    int q = k - 3, j = q / 6, r = q % 6, a = r % 3;
                    float xx = (a == 0) ? x0 : ((a == 1) ? x1 : x2);
                    float arg = (float)(1 << j) * xx;
                    v = (r < 3) ? __sinf(arg) : __cosf(arg);
                } else v = 0.0f;
                ev[i] = v;
            }
            uint4 u0, u1;
            u0.x = packrn(ev[0], ev[1]);  u0.y = packrn(ev[2], ev[3]);
            u0.z = packrn(ev[4], ev[5]);  u0.w = packrn(ev[6], ev[7]);
            u1.x = packrn(ev[8], ev[9]);  u1.y = packrn(ev[10], ev[11]);
            u1.z = packrn(ev[12], ev[13]); u1.w = packrn(ev[14], ev[15]);
            int sw = (cidx & 7) << 4;
            *(uint4*)(buf + ((cidx * 128 + g4 * 32) ^ sw)) = u0;
            *(uint4*)(buf + ((cidx * 128 + g4 * 32 + 16) ^ sw)) = u1;
        }

        // ---- L1: enc(64) -> 32, relu. Read enc fully into regs first.
        f16x8 a0 = ldA(buf, lane, 0);
        f16x8 a1 = ldA(buf, lane, 1);
        // dir-enc -> buf bytes [64,128)/row (safe: a0/a1 already read; this
        // half stays untouched by stD (bytes [0,64)) until L4 consumes it)
        {
            float ev[8];
#pragma unroll
            for (int i = 0; i < 8; i++) {
                int k = g4 * 8 + i;
                float v;
                if (k < 3) v = (k == 0) ? d0 : ((k == 1) ? d1 : d2);
                else if (k < 27) {
                    int q = k - 3, j = q / 6, r = q % 6, a = r % 3;
                    float xx = (a == 0) ? d0 : ((a == 1) ? d1 : d2);
                    float arg = (float)(1 << j) * xx;
                    v = (r < 3) ? __sinf(arg) : __cosf(arg);
                } else v = 0.0f;
                ev[i] = v;
            }
            uint4 u;
            u.x = packrn(ev[0], ev[1]); u.y = packrn(ev[2], ev[3]);
            u.z = packrn(ev[4], ev[5]); u.w = packrn(ev[6], ev[7]);
            *(uint4*)(buf + ((cidx * 128 + 64 + g4 * 16) ^ ((cidx & 7) << 4))) = u;
        }
#pragma unroll
        for (int n = 0; n < 2; n++) {
            float bv = bias[0 + 16 * n + cidx];
            f32x4 acc = {bv, bv, bv, bv};
            acc = MFMA16(a0, ldB(wB, 0, n * 2 + 0, lane), acc);
            acc = MFMA16(a1, ldB(wB, 0, n * 2 + 1, lane), acc);
            stD(buf, 16 * n + cidx, acc, true, g4);
        }

        // ---- L2: 32 -> 33, relu; col0 -> sigma; cols1..32 -> buf[0..31]
        {
            f16x8 a2 = ldA(buf, lane, 0);
#pragma unroll
            for (int n = 0; n < 3; n++) {
                float bv = bias[32 + 16 * n + cidx];
                f32x4 acc = {bv, bv, bv, bv};
                acc = MFMA16(a2, ldB(wB, 4096, n, lane), acc);
                int C = 16 * n + cidx;
                if (C == 0) {
#pragma unroll
                    for (int r = 0; r < 4; r++) sigw[g4 * 4 + r] = fmaxf(acc[r], 0.0f);
                } else if (C <= 32) {
                    stD(buf, C - 1, acc, true, g4);
                }
            }
        }
        // ---- L3: 32 -> 32, no act -> buf[0..31]
        {
            f16x8 a3 = ldA(buf, lane, 0);
#pragma unroll
            for (int n = 0; n < 2; n++) {
                float bv = bias[80 + 16 * n + cidx];
                f32x4 acc = {bv, bv, bv, bv};
                acc = MFMA16(a3, ldB(wB, 7168, n, lane), acc);
                stD(buf, 16 * n + cidx, acc, false, g4);
            }
        }
        // ---- L4: [h3(0..31) | ed(32..63)] -> 32, relu -> buf[0..31]
        {
            f16x8 a4a = ldA(buf, lane, 0);
            f16x8 a4b = ldA(buf, lane, 1);
#pragma unroll
            for (int n = 0; n < 2; n++) {
                float bv = bias[112 + 16 * n + cidx];
                f32x4 acc = {bv, bv, bv, bv};
                acc = MFMA16(a4a, ldB(wB, 9216, n * 2 + 0, lane), acc);
                acc = MFMA16(a4b, ldB(wB, 9216, n * 2 + 1, lane), acc);
                stD(buf, 16 * n + cidx, acc, true, g4);
            }
        }
        // ---- L5: 32 -> 3, sigmoid; + sigma out
        {
            f16x8 a5 = ldA(buf, lane, 0);
            float bv = bias[144 + cidx];
            f32x4 acc = {bv, bv, bv, bv};
            acc = MFMA16(a5, ldB(wB, 13312, 0, lane), acc);
            if (cidx < 3) {
#pragma unroll
                for (int r = 0; r < 4; r++) {
                    int p = g4 * 4 + r;
                    if (p < nv) out[(size_t)idxw[p] * 3 + cidx] = 1.0f / (1.0f + __expf(-acc[r]));
                }
            } else if (cidx == 3) {
#pragma unroll
                for (int r = 0; r < 4; r++) {
                    int p = g4 * 4 + r;
                    if (p < nv) out[(size_t)3 * P + idxw[p]] = sigw[p];
                }
            }
        }
    }
}

extern "C" void kernel_launch(void* const* d_in, const int* in_sizes, int n_in,
                              void* d_out, int out_size, void* d_ws, size_t ws_size,
                              hipStream_t stream) {
    const float* xs = (const float*)d_in[0];
    const float* dv = (const float*)d_in[1];
    const float* w1 = (const float*)d_in[2];
    const float* b1 = (const float*)d_in[3];
    const float* w2 = (const float*)d_in[4];
    const float* b2 = (const float*)d_in[5];
    const float* w3 = (const float*)d_in[6];
    const float* b3 = (const float*)d_in[7];
    const float* w4 = (const float*)d_in[8];
    const float* b4 = (const float*)d_in[9];
    const float* w5 = (const float*)d_in[10];
    const float* b5 = (const float*)d_in[11];
    float* out = (float*)d_out;
    int P = in_sizes[0] / 3;

    int* counts = (int*)d_ws;
    int* offsets = counts + 4096;
    int* cursor = offsets + 4104;
    int* sorted = cursor + 4096;
    int* cellid = sorted + P;

    hipMemsetAsync(counts, 0, 4096 * sizeof(int), stream);

    int blk = 256;
    int grd = (P + blk - 1) / blk;
    k_count<<<grd, blk, 0, stream>>>(xs, counts, cellid, out, P);
    k_scan<<<1, 64, 0, stream>>>(counts, offsets, cursor);
    k_scatter<<<grd, blk, 0, stream>>>(cellid, cursor, sorted, P);
    k_mlp<<<NCELL, 256, 0, stream>>>(xs, dv, w1, b1, w2, b2, w3, b3, w4, b4, w5, b5,
                                     offsets, sorted, out, P);
}